// Round 10
// baseline (542.321 us; speedup 1.0000x reference)
//
#include <hip/hip_runtime.h>
#include <hip/hip_cooperative_groups.h>
#include <hip/hip_bf16.h>
#include <stdint.h>

namespace cg = cooperative_groups;

#define NTOK 4096
#define DDIM 768
#define HDIM 1536
#define NEXP 6
#define NTYPE 32
#define PADROWS 4224
#define MAXT 38        // max 128-row tiles: 4096/128 + 6

typedef __bf16 bf16x8 __attribute__((ext_vector_type(8)));
typedef float f32x4 __attribute__((ext_vector_type(4)));

static __device__ __forceinline__ unsigned short f2bf(float f) {
  union { float f; unsigned u; } v; v.f = f;
  unsigned r = v.u + 0x7FFFu + ((v.u >> 16) & 1u);
  return (unsigned short)(r >> 16);
}

static __device__ __forceinline__ void gload_lds16(const void* g, void* lds) {
  auto* g1 = reinterpret_cast<const __attribute__((address_space(1))) uint32_t*>(
      reinterpret_cast<uintptr_t>(g));
  auto* l3 = reinterpret_cast<__attribute__((address_space(3))) uint32_t*>(
      (uint32_t)reinterpret_cast<uintptr_t>(lds));
  __builtin_amdgcn_global_load_lds(g1, l3, 16, 0, 0);
}

// 64 KB LDS union — phases never overlap within a block
union SMem {
  struct { unsigned short A[2][128 * 64]; unsigned short B[2][128 * 64]; } g;  // 64 KB
  float tr[64][65];                                                            // 16.6 KB
  struct { int ev2g[NTYPE]; int cnt[NEXP]; int off[NEXP]; int cur[NEXP]; } bk;
};

// ---- 8-wave 128x128 grouped-GEMM tile (R2 structure: dbuf, stage-ahead, 1 barrier/step)
// XOR-swizzle ((row&7)<<4) via pre-swizzled per-lane global source; reads apply same XOR.
template <int K, int NDIM, bool PASS2>
static __device__ __forceinline__ void gemm_tile(
    SMem& sm, int tid, int wave, int lane,
    const unsigned short* __restrict__ Asrc,   // xg (natural order) or h (bucketed)
    const unsigned short* __restrict__ Bw,     // [E][NDIM][K] W^T bf16
    const float* __restrict__ bias,
    const int* __restrict__ perm,
    const float* __restrict__ x,
    const float* __restrict__ ralpha,
    unsigned short* __restrict__ hout,
    float* __restrict__ out,
    int e, int base, int cnt, int nt)
{
  constexpr int NK = K / 64;
  const int wm = wave >> 2, wn = wave & 3;     // 2 (M) x 4 (N) wave grid

  const unsigned short* Bbase = Bw + ((size_t)e * NDIM + (size_t)nt * 128) * K;

  f32x4 acc[4][2];
  #pragma unroll
  for (int i = 0; i < 4; ++i)
    #pragma unroll
    for (int j = 0; j < 2; ++j) acc[i][j] = (f32x4){0.f, 0.f, 0.f, 0.f};

  // staging descriptors: 2 chunks/thread for A and B (16 KB each per K-step)
  int rRow[2], rElem[2], rLds[2];
  const unsigned short* aRowPtr[2];
  #pragma unroll
  for (int i = 0; i < 2; ++i) {
    int chunk = i * 512 + tid;
    int o = chunk * 16;
    int row = o >> 7;
    int inb = (o & 127) ^ ((row & 7) << 4);
    rRow[i] = row; rElem[i] = inb >> 1;
    rLds[i] = (i * 512 + wave * 64) * 16;      // wave-uniform dest base
    int grow;
    if (PASS2) { grow = base + row; }                       // h is bucketed, padded
    else { int t = base + row; if (t > NTOK - 1) t = NTOK - 1; grow = perm[t]; }
    aRowPtr[i] = Asrc + (size_t)grow * K;
  }

  auto stage = [&](int kt, int buf) {
    const int k0 = kt * 64;
    #pragma unroll
    for (int i = 0; i < 2; ++i)
      gload_lds16(aRowPtr[i] + k0 + rElem[i], (char*)sm.g.A[buf] + rLds[i]);
    #pragma unroll
    for (int i = 0; i < 2; ++i)
      gload_lds16(Bbase + (size_t)rRow[i] * K + k0 + rElem[i], (char*)sm.g.B[buf] + rLds[i]);
  };

  stage(0, 0);
  __syncthreads();

  int cur = 0;
  for (int kt = 0; kt < NK; ++kt) {
    if (kt + 1 < NK) stage(kt + 1, cur ^ 1);   // issue next tile BEFORE compute
    #pragma unroll
    for (int ks = 0; ks < 2; ++ks) {
      bf16x8 av[4], bv[2];
      const int kb = ks * 64 + ((lane >> 4) << 4);
      #pragma unroll
      for (int mi = 0; mi < 4; ++mi) {
        int row = wm * 64 + mi * 16 + (lane & 15);
        int byte = (row * 128 + kb) ^ ((row & 7) << 4);
        av[mi] = *reinterpret_cast<const bf16x8*>((const char*)sm.g.A[cur] + byte);
      }
      #pragma unroll
      for (int nj = 0; nj < 2; ++nj) {
        int row = wn * 32 + nj * 16 + (lane & 15);
        int byte = (row * 128 + kb) ^ ((row & 7) << 4);
        bv[nj] = *reinterpret_cast<const bf16x8*>((const char*)sm.g.B[cur] + byte);
      }
      #pragma unroll
      for (int mi = 0; mi < 4; ++mi)
        #pragma unroll
        for (int nj = 0; nj < 2; ++nj)
          acc[mi][nj] = __builtin_amdgcn_mfma_f32_16x16x32_bf16(av[mi], bv[nj], acc[mi][nj], 0, 0, 0);
    }
    __syncthreads();                           // next tile landed + buffer reuse safe
    cur ^= 1;
  }

  // epilogue. C/D layout: col = lane&15, row = (lane>>4)*4 + reg
  const int col0 = nt * 128 + wn * 32;
  if constexpr (!PASS2) {
    #pragma unroll
    for (int nj = 0; nj < 2; ++nj) {
      int n = col0 + nj * 16 + (lane & 15);
      float bv = bias[e * NDIM + n];
      #pragma unroll
      for (int mi = 0; mi < 4; ++mi) {
        int rbase = wm * 64 + mi * 16 + ((lane >> 4) << 2);
        #pragma unroll
        for (int rr = 0; rr < 4; ++rr) {
          int row = rbase + rr;
          if (row < cnt) {
            float v = fmaxf(acc[mi][nj][rr] + bv, 0.0f);
            hout[(size_t)(base + row) * NDIM + n] = f2bf(v);
          }
        }
      }
    }
  } else {
    float alpha = 0.05f / (1.0f + expf(-ralpha[e]));
    #pragma unroll
    for (int nj = 0; nj < 2; ++nj) {
      int n = col0 + nj * 16 + (lane & 15);
      float bv = bias[e * NDIM + n];
      #pragma unroll
      for (int mi = 0; mi < 4; ++mi) {
        int rbase = wm * 64 + mi * 16 + ((lane >> 4) << 2);
        #pragma unroll
        for (int rr = 0; rr < 4; ++rr) {
          int row = rbase + rr;
          if (row < cnt) {
            int tok = perm[base + row];
            size_t oi = (size_t)tok * DDIM + n;
            out[oi] = x[oi] + alpha * (acc[mi][nj][rr] + bv);
          }
        }
      }
    }
  }
}

// ---------------- single cooperative mega-kernel ----------------
__global__ __launch_bounds__(512, 4)
void mega_kernel(const float* __restrict__ x, const int* __restrict__ ids,
                 const float* __restrict__ W1, const float* __restrict__ b1,
                 const float* __restrict__ W2, const float* __restrict__ b2,
                 const float* __restrict__ ralpha, const int* __restrict__ ev2g,
                 float* __restrict__ out,
                 unsigned short* __restrict__ w1t, unsigned short* __restrict__ w2t,
                 unsigned short* __restrict__ xg, unsigned short* __restrict__ h,
                 int* __restrict__ perm, int* __restrict__ meta)
{
  __shared__ SMem sm;
  cg::grid_group grid = cg::this_grid();
  const int NB = gridDim.x;
  const int bid = blockIdx.x;
  const int tid = threadIdx.x;
  const int wave = tid >> 6, lane = tid & 63;

  // ======== P0: weight transpose (3456 tiles) + bucket (1) + x convert (64) ========
  for (int task = bid; task < 3521; task += NB) {
    if (task < 3456) {
      // 64x64 f32 transpose tile -> bf16
      const int mat = task / 288;          // 0..5 W1, 6..11 W2
      const int t2 = task % 288;
      const float* src; unsigned short* dst; int R, C, bx, by;
      if (mat < 6) {
        src = W1 + (size_t)mat * 768 * 1536; dst = w1t + (size_t)mat * 768 * 1536;
        R = 768; C = 1536; bx = t2 % 24; by = t2 / 24;
      } else {
        src = W2 + (size_t)(mat - 6) * 768 * 1536; dst = w2t + (size_t)(mat - 6) * 768 * 1536;
        R = 1536; C = 768; bx = t2 % 12; by = t2 / 12;
      }
      const int r0 = by * 64, c0 = bx * 64;
      const int lc = (tid & 15) << 2;
      #pragma unroll
      for (int i = 0; i < 2; ++i) {
        int row = i * 32 + (tid >> 4);
        float4 v = *reinterpret_cast<const float4*>(src + (size_t)(r0 + row) * C + c0 + lc);
        sm.tr[row][lc] = v.x; sm.tr[row][lc + 1] = v.y;
        sm.tr[row][lc + 2] = v.z; sm.tr[row][lc + 3] = v.w;
      }
      __syncthreads();
      const int j = tid >> 3, l8 = (tid & 7) << 3;
      union { unsigned short u[8]; uint4 v; } pk;
      #pragma unroll
      for (int k = 0; k < 8; ++k) pk.u[k] = f2bf(sm.tr[l8 + k][j]);
      *reinterpret_cast<uint4*>(dst + (size_t)(c0 + j) * R + r0 + l8) = pk.v;
      __syncthreads();
    } else if (task == 3456) {
      // bucket: hist + tile table (128-row) + scatter perm
      if (tid < NTYPE) sm.bk.ev2g[tid] = ev2g[tid];
      if (tid < NEXP) { sm.bk.cnt[tid] = 0; sm.bk.cur[tid] = 0; }
      __syncthreads();
      int g[8];
      #pragma unroll
      for (int i = 0; i < 8; ++i) {
        int idx = tid * 8 + i;
        int ty = ids[idx];
        ty = ty < 0 ? 0 : (ty > NTYPE - 1 ? NTYPE - 1 : ty);
        g[i] = sm.bk.ev2g[ty];
        atomicAdd(&sm.bk.cnt[g[i]], 1);
      }
      __syncthreads();
      if (tid == 0) {
        int off = 0, ntl = 0;
        int* table = meta + 21;
        for (int e = 0; e < NEXP; ++e) {
          sm.bk.off[e] = off;
          int c = sm.bk.cnt[e];
          for (int k = 0; k * 128 < c; ++k) {
            int rem = c - k * 128;
            table[ntl * 3 + 0] = e;
            table[ntl * 3 + 1] = off + k * 128;
            table[ntl * 3 + 2] = rem < 128 ? rem : 128;
            ++ntl;
          }
          off += c;
        }
        meta[20] = ntl;
      }
      __syncthreads();
      #pragma unroll
      for (int i = 0; i < 8; ++i) {
        int idx = tid * 8 + i;
        int pos = sm.bk.off[g[i]] + atomicAdd(&sm.bk.cur[g[i]], 1);
        perm[pos] = idx;
      }
    } else {
      // x fp32 -> bf16, natural order; 64 rows per task
      const int R0 = (task - 3457) * 64 + wave * 8;
      #pragma unroll
      for (int rr = 0; rr < 8; ++rr) {
        const int row = R0 + rr;
        const float4* in = reinterpret_cast<const float4*>(x + (size_t)row * DDIM);
        ushort4* op = reinterpret_cast<ushort4*>(xg + (size_t)row * DDIM);
        #pragma unroll
        for (int j = 0; j < 3; ++j) {
          float4 v = in[lane + j * 64];
          ushort4 o;
          o.x = f2bf(v.x); o.y = f2bf(v.y); o.z = f2bf(v.z); o.w = f2bf(v.w);
          op[lane + j * 64] = o;
        }
      }
    }
  }

  __threadfence();
  grid.sync();

  // ======== P1: gemm1  h = relu(xg @ W1 + b1), grouped ========
  const int ntiles = *(volatile int*)(meta + 20);
  const int* table = meta + 21;
  for (int task = bid; task < ntiles * 12; task += NB) {
    const int nt = task / ntiles, mt = task % ntiles;   // nt-major: share B-panel
    const int e = table[mt * 3 + 0], base = table[mt * 3 + 1], cnt = table[mt * 3 + 2];
    gemm_tile<DDIM, HDIM, false>(sm, tid, wave, lane, xg, w1t, b1, perm, x, ralpha,
                                 h, out, e, base, cnt, nt);
  }

  __threadfence();
  grid.sync();

  // ======== P2: gemm2  out = x + alpha*(h @ W2 + b2), grouped ========
  for (int task = bid; task < ntiles * 6; task += NB) {
    const int nt = task / ntiles, mt = task % ntiles;
    const int e = table[mt * 3 + 0], base = table[mt * 3 + 1], cnt = table[mt * 3 + 2];
    gemm_tile<HDIM, DDIM, true>(sm, tid, wave, lane, h, w2t, b2, perm, x, ralpha,
                                nullptr, out, e, base, cnt, nt);
  }

  __threadfence();
  grid.sync();

  // ======== P3: L2-normalize each 768-row of out (1 row per wave) ========
  for (int task = bid; task < 512; task += NB) {
    const int tok = task * 8 + wave;
    float4* p = reinterpret_cast<float4*>(out) + (size_t)tok * 192;
    float4 a = p[lane], b = p[lane + 64], c = p[lane + 128];
    float ss = a.x * a.x + a.y * a.y + a.z * a.z + a.w * a.w
             + b.x * b.x + b.y * b.y + b.z * b.z + b.w * b.w
             + c.x * c.x + c.y * c.y + c.z * c.z + c.w * c.w;
    #pragma unroll
    for (int off = 32; off; off >>= 1) ss += __shfl_xor(ss, off);
    const float s = 1.0f / fmaxf(sqrtf(ss), 1e-12f);
    a.x *= s; a.y *= s; a.z *= s; a.w *= s;
    b.x *= s; b.y *= s; b.z *= s; b.w *= s;
    c.x *= s; c.y *= s; c.z *= s; c.w *= s;
    p[lane] = a; p[lane + 64] = b; p[lane + 128] = c;
  }
}

// ---------------- launch ----------------

extern "C" void kernel_launch(void* const* d_in, const int* in_sizes, int n_in,
                              void* d_out, int out_size, void* d_ws, size_t ws_size,
                              hipStream_t stream) {
  const float* x      = (const float*)d_in[0];
  const int*   ids    = (const int*)d_in[1];
  const float* W1     = (const float*)d_in[2];
  const float* b1     = (const float*)d_in[3];
  const float* W2     = (const float*)d_in[4];
  const float* b2     = (const float*)d_in[5];
  const float* ralpha = (const float*)d_in[6];
  const int*   ev2g   = (const int*)d_in[7];
  float* out = (float*)d_out;
  char* ws = (char*)d_ws;

  unsigned short* w1t = (unsigned short*)(ws);                 // [6][1536][768] bf16
  unsigned short* w2t = (unsigned short*)(ws + 14155776);      // [6][768][1536] bf16
  unsigned short* xg  = (unsigned short*)(ws + 28311552);      // [4096][768]  bf16 natural
  unsigned short* h   = (unsigned short*)(ws + 34799616);      // [4224][1536] bf16 bucketed
  int* perm = (int*)(ws + 47775744);
  int* meta = (int*)(ws + 47808512);

  int nb = 0;
  if (hipOccupancyMaxActiveBlocksPerMultiprocessor(&nb, mega_kernel, 512, 0) != hipSuccess || nb < 1)
    nb = 1;
  const int grid = nb >= 2 ? 512 : 256;

  void* args[] = {
    (void*)&x, (void*)&ids, (void*)&W1, (void*)&b1, (void*)&W2, (void*)&b2,
    (void*)&ralpha, (void*)&ev2g, (void*)&out,
    (void*)&w1t, (void*)&w2t, (void*)&xg, (void*)&h, (void*)&perm, (void*)&meta
  };
  hipLaunchCooperativeKernel(mega_kernel, dim3(grid), dim3(512), args, 0, stream);
}